// Round 17
// baseline (149.078 us; speedup 1.0000x reference)
//
#include <hip/hip_runtime.h>
#include <math.h>

constexpr int Bsz = 8;
constexpr int Cc  = 512;   // input channels
constexpr int Tt  = 2048;  // sequence length
constexpr int Kk  = 512;   // key/value size
constexpr float SCALE = 0.0441941738241592f; // 1/sqrt(512)

typedef __attribute__((ext_vector_type(8))) _Float16 f16x8;
typedef __attribute__((ext_vector_type(4))) float f32x4;
typedef __attribute__((ext_vector_type(4))) unsigned short us4;
typedef __attribute__((ext_vector_type(8))) unsigned short us8;

#define MFMA16F(a,b,c) __builtin_amdgcn_mfma_f32_16x16x32_f16((a),(b),(c),0,0,0)

__device__ __forceinline__ unsigned short f2h(float f) {
    union { _Float16 h; unsigned short u; } v;
    v.h = (_Float16)f;          // IEEE RNE
    return v.u;
}
__device__ __forceinline__ float h2f(unsigned short u) {
    union { unsigned short u; _Float16 h; } v; v.u = u; return (float)v.h;
}

// ---------------------------------------------------------------------------
// Swizzled staging into linear LDS (pitch 32 shorts, 64-B rows). LDS slot s
// holds global slot s ^ ((row>>1)&3); global_load_lds writes linearly, so the
// swizzle is applied to the per-lane GLOBAL source address; fragment reads
// XOR the same pattern (fragSw).
// ---------------------------------------------------------------------------
__device__ __forceinline__ void stageP(const short* __restrict__ g, int stride,
                                       short* lds, int wid, int lane)
{
    #pragma unroll
    for (int c = 0; c < 2; ++c) {
        int row0 = (wid * 2 + c) * 16;
        int row  = row0 + (lane >> 2);
        int slot = lane & 3;
        int srcslot = slot ^ ((row >> 1) & 3);
        const short* src = g + (size_t)row * stride + srcslot * 8;
        __builtin_amdgcn_global_load_lds(
            (const __attribute__((address_space(1))) unsigned int*)src,
            (__attribute__((address_space(3))) unsigned int*)(lds + row0 * 32),
            16, 0, 0);
    }
}

__device__ __forceinline__ void stage256(const short* __restrict__ g, int stride,
                                         short* lds, int wid, int lane)
{
    #pragma unroll
    for (int c = 0; c < 2; ++c) {
        int row0 = (wid * 2 + c) * 16;
        int row  = row0 + (lane >> 2);
        int slot = lane & 3;
        int srcslot = slot ^ ((row >> 1) & 3);
        const short* src = g + (size_t)row * stride + srcslot * 8;
        __builtin_amdgcn_global_load_lds(
            (const __attribute__((address_space(1))) unsigned int*)src,
            (__attribute__((address_space(3))) unsigned int*)(lds + row0 * 32),
            16, 0, 0);
    }
}

__device__ __forceinline__ void stage128w8(const short* __restrict__ g, int stride,
                                           short* lds, int wid, int lane)
{
    int row0 = wid * 16;
    int row  = row0 + (lane >> 2);
    int slot = lane & 3;
    int srcslot = slot ^ ((row >> 1) & 3);
    const short* src = g + (size_t)row * stride + srcslot * 8;
    __builtin_amdgcn_global_load_lds(
        (const __attribute__((address_space(1))) unsigned int*)src,
        (__attribute__((address_space(3))) unsigned int*)(lds + row0 * 32),
        16, 0, 0);
}

__device__ __forceinline__ f16x8 fragSw(const short* lds, int r, int slot)
{
    return *(const f16x8*)&lds[r * 32 + ((slot ^ ((r >> 1) & 3)) << 3)];
}

// ---------------------------------------------------------------------------
// Kernel 0: fused {transpose x -> xTh fp16} + {W fp32 -> fp16}.
// ---------------------------------------------------------------------------
__global__ __launch_bounds__(256) void transpose_prep(
    const float* __restrict__ x, short* __restrict__ xTh,
    const float* __restrict__ Wq, const float* __restrict__ Wk,
    const float* __restrict__ Wv, short* __restrict__ Wh)
{
    const int id = blockIdx.x;
    const int tid = threadIdx.x;
    __shared__ float tile[64 * 69];

    if (id < 2048) {
        const int b = id & 7;
        const int r = id >> 3;
        const int t0 = (r & 31) * 64, c0 = (r >> 5) * 64;
        const float* xb = x + (size_t)b * Cc * Tt;
        #pragma unroll
        for (int p = 0; p < 4; ++p) {
            int idx = tid + p * 256;
            int cr = idx >> 4, ch = idx & 15;
            float4 v = *(const float4*)&xb[(size_t)(c0 + cr) * Tt + t0 + ch * 4];
            tile[cr * 69 + ch * 4 + 0] = v.x;
            tile[cr * 69 + ch * 4 + 1] = v.y;
            tile[cr * 69 + ch * 4 + 2] = v.z;
            tile[cr * 69 + ch * 4 + 3] = v.w;
        }
        __syncthreads();
        #pragma unroll
        for (int p = 0; p < 4; ++p) {
            int idx = tid + p * 256;
            int t = idx >> 4, cg = idx & 15;
            us4 h;
            h.x = f2h(tile[(cg * 4 + 0) * 69 + t]);
            h.y = f2h(tile[(cg * 4 + 1) * 69 + t]);
            h.z = f2h(tile[(cg * 4 + 2) * 69 + t]);
            h.w = f2h(tile[(cg * 4 + 3) * 69 + t]);
            size_t o = (size_t)b * Tt * Cc + (size_t)(t0 + t) * Cc + c0 + cg * 4;
            *(us4*)&xTh[o] = h;
        }
    } else {
        int i = ((id - 2048) * 256 + tid) * 8;
        int which = i >> 18;
        int rem = i & ((1 << 18) - 1);
        const float* src = which == 0 ? Wq : (which == 1 ? Wk : Wv);
        float4 a = *(const float4*)&src[rem];
        float4 c = *(const float4*)&src[rem + 4];
        us8 h;
        h[0] = f2h(a.x); h[1] = f2h(a.y); h[2] = f2h(a.z); h[3] = f2h(a.w);
        h[4] = f2h(c.x); h[5] = f2h(c.y); h[6] = f2h(c.z); h[7] = f2h(c.w);
        *(us8*)&Wh[i] = h;
    }
}

// ---------------------------------------------------------------------------
// Kernel 1: Q/K projection, 256x128 tile, 512 threads (8 waves), fp16 MFMA,
// 2-phase double-buffered K-loop. b = id&7 (XCD).
// ---------------------------------------------------------------------------
__global__ __launch_bounds__(512) void qk_mfma(
    const short* __restrict__ xTh, const short* __restrict__ Wh_g,
    const float* __restrict__ bq, const float* __restrict__ bk,
    unsigned short* __restrict__ Qh, unsigned short* __restrict__ Kh)
{
    const int id = blockIdx.x;
    const int b = id & 7;
    const int rem = id >> 3;           // 0..63
    const int which = rem >> 5;        // 0..1
    const int r2 = rem & 31;
    const int tb0 = (r2 & 7) * 256;
    const int kb0 = (r2 >> 3) * 128;
    const int tid = threadIdx.x, lane = tid & 63, wid = tid >> 6;
    const int wr = (wid >> 1) * 64, wc = (wid & 1) * 64;

    __shared__ __align__(16) short sbuf[24576];   // 48 KB
    short* As0 = sbuf;            // 256x32
    short* As1 = sbuf + 8192;
    short* Bs0 = sbuf + 16384;    // 128x32
    short* Bs1 = sbuf + 20480;

    const short* Wp = Wh_g + (size_t)which * Kk * Cc;
    const short* Ag = xTh + (size_t)b * Tt * Cc + (size_t)tb0 * Cc;
    const short* Bg = Wp + (size_t)kb0 * Cc;

    f32x4 acc[4][4];
    #pragma unroll
    for (int i = 0; i < 4; ++i)
        #pragma unroll
        for (int j = 0; j < 4; ++j) acc[i][j] = (f32x4){0.f, 0.f, 0.f, 0.f};

    stage256(Ag, Cc, As0, wid, lane);
    stage128w8(Bg, Cc, Bs0, wid, lane);
    __syncthreads();

    int cur = 0;
    for (int step = 0; step < Cc / 32; ++step) {
        short* Ac = cur ? As1 : As0;
        short* Bc = cur ? Bs1 : Bs0;
        if (step + 1 < Cc / 32) {
            int c0 = (step + 1) * 32;
            stage256(Ag + c0, Cc, cur ? As0 : As1, wid, lane);
            stage128w8(Bg + c0, Cc, cur ? Bs0 : Bs1, wid, lane);
        }
        const int fr = lane & 15, slot = lane >> 4;
        f16x8 a4[4], b4[4];
        #pragma unroll
        for (int i = 0; i < 4; ++i) {
            a4[i] = fragSw(Ac, wr + i * 16 + fr, slot);
            b4[i] = fragSw(Bc, wc + i * 16 + fr, slot);
        }
        #pragma unroll
        for (int i = 0; i < 4; ++i)
            #pragma unroll
            for (int j = 0; j < 4; ++j)
                acc[i][j] = MFMA16F(a4[i], b4[j], acc[i][j]);
        __syncthreads();
        cur ^= 1;
    }

    const float* bg = (which == 0) ? bq : bk;
    unsigned short* Oh = ((which == 0) ? Qh : Kh) + (size_t)b * Tt * Kk;
    const int g = lane >> 4;
    #pragma unroll
    for (int j = 0; j < 4; ++j) {
        int k = kb0 + wc + j * 16 + (lane & 15);
        float bias = bg[k];
        #pragma unroll
        for (int i = 0; i < 4; ++i)
            #pragma unroll
            for (int r = 0; r < 4; ++r) {
                int t = tb0 + wr + i * 16 + g * 4 + r;
                Oh[(size_t)t * Kk + k] = f2h(acc[i][j][r] + bias);
            }
    }
}

// ---------------------------------------------------------------------------
// Kernel 2: heterogeneous 512-thread grid.
// ids [0,576):    scores tiles 256x128 -> e fp16 + column partial sums.
// ids [576,832):  V projection 256x128 -> Vt.
// ids [832,1088): zerofill of the w upper triangle: block (b,qc) zeros rows
//                 [qc*64, qc*64+64) cols [(qc+1)*64, 2048). Chunks
//                 overlapping the xTh/Wh scratch (b==0, or b==1 && qc<3)
//                 are skipped here and handled in the inv_vscale launch.
// ---------------------------------------------------------------------------
__global__ __launch_bounds__(512) void scores_vproj(
    const unsigned short* __restrict__ Qh, const unsigned short* __restrict__ Kh,
    const short* __restrict__ xTh, const short* __restrict__ Wh_g,
    const float* __restrict__ bv,
    unsigned short* __restrict__ e, float* __restrict__ psum,
    short* __restrict__ Vt, float* __restrict__ S)
{
    const int id = blockIdx.x;
    const int tid = threadIdx.x, lane = tid & 63, wid = tid >> 6;
    const int wr = (wid >> 1) * 64, wc = (wid & 1) * 64;

    __shared__ __align__(16) short sbuf[24576];   // 48 KB pool
    short* As0 = sbuf;            // 256x32
    short* As1 = sbuf + 8192;
    short* Bs0 = sbuf + 16384;    // 128x32
    short* Bs1 = sbuf + 20480;

    if (id < 576) {
        // ----- scores role -----
        const int b = id & 7;
        const int rem = id >> 3;           // 0..71 -> (qb, ti), ti <= 2qb+1
        int qb = (int)((sqrtf(4.f * rem + 1.f) - 1.f) * 0.5f);
        while ((qb + 1) * (qb + 2) <= rem) ++qb;
        while (qb * (qb + 1) > rem) --qb;
        const int ti = rem - qb * (qb + 1);
        const int q0 = qb * 256, t0 = ti * 128;
        const bool mm = (ti >= 2 * qb);    // tile may touch the mask

        const short* Qg = (const short*)Qh + (size_t)b * Tt * Kk + (size_t)q0 * Kk;
        const short* Kg = (const short*)Kh + (size_t)b * Tt * Kk + (size_t)t0 * Kk;

        f32x4 acc[4][4];
        #pragma unroll
        for (int i = 0; i < 4; ++i)
            #pragma unroll
            for (int j = 0; j < 4; ++j) acc[i][j] = (f32x4){0.f, 0.f, 0.f, 0.f};

        stage256(Qg, Kk, As0, wid, lane);
        stage128w8(Kg, Kk, Bs0, wid, lane);
        __syncthreads();

        int cur = 0;
        for (int step = 0; step < Kk / 32; ++step) {
            short* Qc = cur ? As1 : As0;
            short* Kc = cur ? Bs1 : Bs0;
            if (step + 1 < Kk / 32) {
                int k0 = (step + 1) * 32;
                stage256(Qg + k0, Kk, cur ? As0 : As1, wid, lane);
                stage128w8(Kg + k0, Kk, cur ? Bs0 : Bs1, wid, lane);
            }
            const int fr = lane & 15, slot = lane >> 4;
            f16x8 qf[4], kf[4];
            #pragma unroll
            for (int i = 0; i < 4; ++i) {
                qf[i] = fragSw(Qc, wr + i * 16 + fr, slot);
                kf[i] = fragSw(Kc, wc + i * 16 + fr, slot);
            }
            __builtin_amdgcn_s_setprio(1);
            #pragma unroll
            for (int i = 0; i < 4; ++i)
                #pragma unroll
                for (int j = 0; j < 4; ++j)
                    acc[i][j] = MFMA16F(qf[i], kf[j], acc[i][j]);
            __builtin_amdgcn_s_setprio(0);
            __syncthreads();
            cur ^= 1;
        }

        unsigned short* eb = e + (size_t)b * Tt * Tt;
        const int fcol = lane & 15, g = lane >> 4;

        // pass 1: psum for all waves; waves wid<4 (rows 0-127) deposit e
        // into the LDS tile [128][136].
        float psumv[4];
        #pragma unroll
        for (int j = 0; j < 4; ++j) {
            int tl = wc + j * 16 + fcol;
            int t = t0 + tl;
            float su = 0.f;
            #pragma unroll
            for (int i = 0; i < 4; ++i)
                #pragma unroll
                for (int r = 0; r < 4; ++r) {
                    int ql = wr + i * 16 + g * 4 + r;
                    int q = q0 + ql;
                    float sv = acc[i][j][r] * SCALE;
                    float ev = __expf(fminf(sv, 11.0f));
                    bool live = (!mm || q >= t);
                    if (live) su += ev;
                    if (wid < 4) sbuf[ql * 136 + tl] = live ? (short)f2h(ev) : (short)0;
                }
            su += __shfl_xor(su, 16, 64);
            su += __shfl_xor(su, 32, 64);
            psumv[j] = su;
        }
        if (lane < 16) {
            const int chunk = qb * 4 + (wid >> 1);
            #pragma unroll
            for (int j = 0; j < 4; ++j) {
                int t = t0 + wc + j * 16 + lane;
                psum[((size_t)b * 32 + chunk) * Tt + t] = psumv[j];
            }
        }
        __syncthreads();

        // store rows 0..127 (coalesced us8 rows)
        #pragma unroll
        for (int c = 0; c < 4; ++c) {
            int chunk = tid + 512 * c;          // 0..2047
            int ql = chunk >> 4, toct = chunk & 15;
            us8 v = *(const us8*)&sbuf[ql * 136 + toct * 8];
            *(us8*)&eb[(size_t)(q0 + ql) * Tt + t0 + toct * 8] = v;
        }
        __syncthreads();

        // pass 2: waves wid>=4 deposit rows 128-255 (shifted by -128)
        if (wid >= 4) {
            #pragma unroll
            for (int j = 0; j < 4; ++j) {
                int tl = wc + j * 16 + fcol;
                int t = t0 + tl;
                #pragma unroll
                for (int i = 0; i < 4; ++i)
                    #pragma unroll
                    for (int r = 0; r < 4; ++r) {
                        int ql = wr + i * 16 + g * 4 + r;
                        int q = q0 + ql;
                        float sv = acc[i][j][r] * SCALE;
                        float ev = __expf(fminf(sv, 11.0f));
                        bool live = (!mm || q >= t);
                        sbuf[(ql - 128) * 136 + tl] = live ? (short)f2h(ev) : (short)0;
                    }
            }
        }
        __syncthreads();

        // store rows 128..255
        #pragma unroll
        for (int c = 0; c < 4; ++c) {
            int chunk = tid + 512 * c;
            int ql = chunk >> 4, toct = chunk & 15;
            us8 v = *(const us8*)&sbuf[ql * 136 + toct * 8];
            *(us8*)&eb[(size_t)(q0 + 128 + ql) * Tt + t0 + toct * 8] = v;
        }
    } else if (id < 832) {
        // ----- V projection role: 256 v-rows x 128 t-cols -----
        const int id2 = id - 576;
        const int b = id2 & 7;
        const int r2 = id2 >> 3;           // 0..31
        const int tb0 = (r2 & 15) * 128;
        const int kb0 = (r2 >> 4) * 256;

        const short* Wp = Wh_g + (size_t)2 * Kk * Cc;
        const short* Ag = Wp + (size_t)kb0 * Cc;
        const short* Bg = xTh + (size_t)b * Tt * Cc + (size_t)tb0 * Cc;

        f32x4 acc[4][4];
        #pragma unroll
        for (int i = 0; i < 4; ++i)
            #pragma unroll
            for (int j = 0; j < 4; ++j) acc[i][j] = (f32x4){0.f, 0.f, 0.f, 0.f};

        stage256(Ag, Cc, As0, wid, lane);
        stage128w8(Bg, Cc, Bs0, wid, lane);
        __syncthreads();

        int cur = 0;
        for (int step = 0; step < Cc / 32; ++step) {
            short* Ac = cur ? As1 : As0;
            short* Bc = cur ? Bs1 : Bs0;
            if (step + 1 < Cc / 32) {
                int c0 = (step + 1) * 32;
                stage256(Ag + c0, Cc, cur ? As0 : As1, wid, lane);
                stage128w8(Bg + c0, Cc, cur ? Bs0 : Bs1, wid, lane);
            }
            const int fr = lane & 15, slot = lane >> 4;
            f16x8 a4[4], b4[4];
            #pragma unroll
            for (int i = 0; i < 4; ++i) {
                a4[i] = fragSw(Ac, wr + i * 16 + fr, slot);
                b4[i] = fragSw(Bc, wc + i * 16 + fr, slot);
            }
            __builtin_amdgcn_s_setprio(1);
            #pragma unroll
            for (int i = 0; i < 4; ++i)
                #pragma unroll
                for (int j = 0; j < 4; ++j)
                    acc[i][j] = MFMA16F(a4[i], b4[j], acc[i][j]);
            __builtin_amdgcn_s_setprio(0);
            __syncthreads();
            cur ^= 1;
        }

        short* Vb = Vt + (size_t)b * Kk * Tt;
        const int g = lane >> 4;
        #pragma unroll
        for (int i = 0; i < 4; ++i)
            #pragma unroll
            for (int r = 0; r < 4; ++r) {
                int vv = kb0 + wr + i * 16 + g * 4 + r;
                float bias = bv[vv];
                #pragma unroll
                for (int j = 0; j < 4; ++j) {
                    int t = tb0 + wc + j * 16 + (lane & 15);
                    Vb[(size_t)vv * Tt + t] = (short)f2h(acc[i][j][r] + bias);
                }
            }
    } else {
        // ----- zerofill role: upper-tri w chunks outside the scratch -----
        const int id2 = id - 832;          // 0..255
        const int b = id2 & 7;
        const int qc = id2 >> 3;           // 0..31
        if (b == 0 || (b == 1 && qc < 3)) return;  // overlaps scratch
        const int q0 = qc * 64;
        const int cstart = (qc + 1) * 64;
        float* Sb = S + (size_t)b * Tt * Tt;
        f32x4 z = (f32x4){0.f, 0.f, 0.f, 0.f};
        const int c4 = cstart + tid * 4;   // one 2048-float sweep covers row
        if (c4 < 2048) {
            for (int row = 0; row < 64; ++row)
                __builtin_nontemporal_store(z,
                    (f32x4*)&Sb[(size_t)(q0 + row) * Tt + c4]);
        }
    }
}

// ---------------------------------------------------------------------------
// Kernel 3: fused {combine psum -> inv} + {V *= inv[t]} + deferred zerofill
// of the 35 scratch-overlapping w chunks (scratch dead by this launch).
// ---------------------------------------------------------------------------
__global__ __launch_bounds__(256) void inv_vscale(
    const float* __restrict__ psum, float* __restrict__ mi,
    unsigned short* __restrict__ Vt, float* __restrict__ S)
{
    const int id = blockIdx.x;
    const int tid = threadIdx.x;

    if (id >= 256) {
        // ----- deferred zerofill: b==0 qc 0..31, b==1 qc 0..2 -----
        const int id2 = id - 256;          // 0..34
        const int b  = (id2 < 32) ? 0 : 1;
        const int qc = (id2 < 32) ? id2 : (id2 - 32);
        const int q0 = qc * 64;
        const int cstart = (qc + 1) * 64;
        float* Sb = S + (size_t)b * Tt * Tt;
        f32x4 z = (f32x4){0.f, 0.f, 0.f, 0.f};
        for (int row = 0; row < 64; ++row)
            for (int c4 = cstart + tid * 4; c4 < 2048; c4 += 1024)
                __builtin_nontemporal_store(z,
                    (f32x4*)&Sb[(size_t)(q0 + row) * Tt + c4]);
        return;
    }

    const int b  = id & 7;
    const int tc = (id >> 3) & 7;
    const int vq = id >> 6;
    const int t = tc * 256 + tid;

    __shared__ float invs[256];
    float s = 0.f;
    for (int c = (t >> 6); c < 32; ++c)
        s += psum[((size_t)b * 32 + c) * Tt + t];
    float inv = 1.0f / s;
    invs[tid] = inv;
    if (vq == 0) mi[b * Tt + t] = inv;
    __syncthreads();

    const int toff = (tid & 63) * 4;
    const float i0 = invs[toff], i1 = invs[toff + 1];
    const float i2 = invs[toff + 2], i3 = invs[toff + 3];
    unsigned short* Vb = (unsigned short*)Vt + (size_t)b * Kk * Tt + tc * 256;
    #pragma unroll 4
    for (int it = 0; it < 32; ++it) {
        int row = vq * 128 + (tid >> 6) + it * 4;
        unsigned short* p = Vb + (size_t)row * Tt + toff;
        us4 v = *(us4*)p;
        v.x = f2h(h2f(v.x) * i0);
        v.y = f2h(h2f(v.y) * i1);
        v.z = f2h(h2f(v.z) * i2);
        v.w = f2h(h2f(v.w) * i3);
        *(us4*)p = v;
    }
}

// ---------------------------------------------------------------------------
// Kernel 4: pv with fused w-emit. Block (b, qi, vt), heavy-first qi order.
// Per K-step the staged e-tile (LDS) is also converted to fp32 w = e*inv and
// stored by the block with vt == (step & 3) — each step's 32-col window is
// emitted exactly once, work balanced across the 4 vt blocks.
// ---------------------------------------------------------------------------
__global__ __launch_bounds__(256) void pv_mfma(
    const short* __restrict__ Vt, const unsigned short* __restrict__ e,
    const float* __restrict__ mi, float* __restrict__ S,
    float* __restrict__ out0)
{
    const int id = blockIdx.x;
    const int tid = threadIdx.x;
    const int b = id & 7;
    const int rem = id >> 3;           // 0..63
    const int vt = rem & 3, qi = 15 - (rem >> 2);   // heavy first
    const int qb0 = qi * 128, vb0 = vt * 128;
    const int lane = tid & 63, wid = tid >> 6;
    const int wr = (wid >> 1) * 64, wc = (wid & 1) * 64;

    __shared__ __align__(16) short Vs[2][128 * 32];
    __shared__ __align__(16) short Ws[2][128 * 32];

    const short* Vg = Vt + (size_t)b * Kk * Tt + (size_t)vb0 * Tt;
    const short* Wg = (const short*)e + ((size_t)b * Tt + qb0) * Tt;
    float* Sb = S + (size_t)b * Tt * Tt;

    f32x4 acc[4][4];
    #pragma unroll
    for (int i = 0; i < 4; ++i)
        #pragma unroll
        for (int j = 0; j < 4; ++j) acc[i][j] = (f32x4){0.f, 0.f, 0.f, 0.f};

    const int nsteps = (qb0 + 128) / 32;
    stageP(Vg, Tt, Vs[0], wid, lane);
    stageP(Wg, Tt, Ws[0], wid, lane);
    __syncthreads();

    int cur = 0;
    for (int s = 0; s < nsteps; ++s) {
        if (s + 1 < nsteps) {
            int t0 = (s + 1) * 32;
            stageP(Vg + t0, Tt, Vs[cur ^ 1], wid, lane);
            stageP(Wg + t0, Tt, Ws[cur ^ 1], wid, lane);
        }
        const int fr = lane & 15, slot = lane >> 4;
        f16x8 av[4], bw[4];
        #pragma unroll
        for (int i = 0; i < 4; ++i) {
            av[i] = fragSw(Vs[cur], wr + i * 16 + fr, slot);
            bw[i] = fragSw(Ws[cur], wc + i * 16 + fr, slot);
        }
        __builtin_amdgcn_s_setprio(1);
        #pragma unroll
        for (int i = 0; i < 4; ++i)
            #pragma unroll
            for (int j = 0; j < 4; ++j)
                acc[i][j] = MFMA16F(av[i], bw[j], acc[i][j]);
        __builtin_amdgcn_s_setprio(0);

        if ((s & 3) == vt) {
            // emit w rows [qb0,qb0+128) cols [s*32, s*32+32) from LDS e-tile
            const int t0c = s * 32;
            #pragma unroll
            for (int k = 0; k < 4; ++k) {
                int f4 = tid + 256 * k;          // 0..1023
                int row = f4 >> 3, c4 = (f4 & 7) * 4;
                int slotg = c4 >> 3, woff = c4 & 7;
                us4 ev = *(const us4*)&Ws[cur][row * 32 +
                    ((slotg ^ ((row >> 1) & 3)) << 3) + woff];
                float4 iv = *(const float4*)&mi[b * Tt + t0c + c4];
                f32x4 o;
                o[0] = h2f(ev.x) * iv.x; o[1] = h2f(ev.y) * iv.y;
                o[2] = h2f(ev.z) * iv.z; o[3] = h2f(ev.w) * iv.w;
                __builtin_nontemporal_store(o,
                    (f32x4*)&Sb[(size_t)(qb0 + row) * Tt + t0c + c4]);
            }
        }
        __syncthreads();
        cur ^= 1;
    }

    float* ob = out0 + (size_t)b * Kk * Tt;
    #pragma unroll
    for (int i = 0; i < 4; ++i)
        #pragma unroll
        for (int j = 0; j < 4; ++j)
            #pragma unroll
            for (int r = 0; r < 4; ++r) {
                int vv = vb0 + wr + i * 16 + (lane >> 4) * 4 + r;
                int q  = qb0 + wc + j * 16 + (lane & 15);
                __builtin_nontemporal_store(acc[i][j][r],
                                            &ob[(size_t)vv * Tt + q]);
            }
}

// ---------------------------------------------------------------------------
extern "C" void kernel_launch(void* const* d_in, const int* in_sizes, int n_in,
                              void* d_out, int out_size, void* d_ws, size_t ws_size,
                              hipStream_t stream)
{
    const float* x  = (const float*)d_in[0];
    const float* Wq = (const float*)d_in[1];
    const float* bq = (const float*)d_in[2];
    const float* Wk = (const float*)d_in[3];
    const float* bk = (const float*)d_in[4];
    const float* Wv = (const float*)d_in[5];
    const float* bv = (const float*)d_in[6];

    float* out0 = (float*)d_out;                        // [B][V][T]
    float* w    = out0 + (size_t)Bsz * Kk * Tt;         // [B][T][T]

    // Scratch at the START of the w region (first ~4.59M floats = b=0's w +
    // b=1 rows <192). Last reader is scores_vproj (vproj reads xTh); all w
    // writes to that span happen in later launches (inv_vscale zerofill +
    // pv_mfma emit).
    short* xTh  = (short*)w;                            // [B][T][C] fp16
    short* Wh_g = xTh + (size_t)Bsz * Tt * Cc;          // [3][K][C] fp16

    const size_t N = (size_t)Bsz * Tt * Kk;
    unsigned short* Qh = (unsigned short*)d_ws;         // [B][T][K] fp16
    unsigned short* Kh = Qh + N;
    short* Vt = (short*)(Kh + N);                       // [B][V][T] fp16
    float* psum = (float*)(Vt + N);                     // [B][32][T]
    float* mi   = psum + (size_t)Bsz * 32 * Tt;         // [B][T]
    unsigned short* e = (unsigned short*)(mi + (size_t)Bsz * Tt); // [B][T][T] fp16

    transpose_prep<<<dim3(2048 + 384), dim3(256), 0, stream>>>(
        x, xTh, Wq, Wk, Wv, Wh_g);
    qk_mfma<<<dim3(512), dim3(512), 0, stream>>>(
        xTh, Wh_g, bq, bk, Qh, Kh);
    scores_vproj<<<dim3(576 + 256 + 256), dim3(512), 0, stream>>>(
        Qh, Kh, xTh, Wh_g, bv, e, psum, Vt, w);
    inv_vscale<<<dim3(256 + 35), dim3(256), 0, stream>>>(
        psum, mi, (unsigned short*)Vt, w);
    pv_mfma<<<dim3(512), dim3(256), 0, stream>>>(Vt, e, mi, w, out0);
}

// Round 18
// 147.144 us; speedup vs baseline: 1.0131x; 1.0131x over previous
//
#include <hip/hip_runtime.h>
#include <math.h>

constexpr int Bsz = 8;
constexpr int Cc  = 512;   // input channels
constexpr int Tt  = 2048;  // sequence length
constexpr int Kk  = 512;   // key/value size
constexpr float SCALE = 0.0441941738241592f; // 1/sqrt(512)

typedef __attribute__((ext_vector_type(8))) _Float16 f16x8;
typedef __attribute__((ext_vector_type(4))) float f32x4;
typedef __attribute__((ext_vector_type(4))) unsigned short us4;
typedef __attribute__((ext_vector_type(8))) unsigned short us8;

#define MFMA16F(a,b,c) __builtin_amdgcn_mfma_f32_16x16x32_f16((a),(b),(c),0,0,0)

__device__ __forceinline__ unsigned short f2h(float f) {
    union { _Float16 h; unsigned short u; } v;
    v.h = (_Float16)f;          // IEEE RNE
    return v.u;
}
__device__ __forceinline__ float h2f(unsigned short u) {
    union { unsigned short u; _Float16 h; } v; v.u = u; return (float)v.h;
}

// ---------------------------------------------------------------------------
// Swizzled staging into linear LDS (pitch 32 shorts, 64-B rows). LDS slot s
// holds global slot s ^ ((row>>1)&3); global_load_lds writes linearly, so the
// swizzle is applied to the per-lane GLOBAL source address; fragment reads
// XOR the same pattern (fragSw).
// ---------------------------------------------------------------------------
__device__ __forceinline__ void stageP(const short* __restrict__ g, int stride,
                                       short* lds, int wid, int lane)
{
    #pragma unroll
    for (int c = 0; c < 2; ++c) {
        int row0 = (wid * 2 + c) * 16;
        int row  = row0 + (lane >> 2);
        int slot = lane & 3;
        int srcslot = slot ^ ((row >> 1) & 3);
        const short* src = g + (size_t)row * stride + srcslot * 8;
        __builtin_amdgcn_global_load_lds(
            (const __attribute__((address_space(1))) unsigned int*)src,
            (__attribute__((address_space(3))) unsigned int*)(lds + row0 * 32),
            16, 0, 0);
    }
}

__device__ __forceinline__ void stage256(const short* __restrict__ g, int stride,
                                         short* lds, int wid, int lane)
{
    #pragma unroll
    for (int c = 0; c < 2; ++c) {
        int row0 = (wid * 2 + c) * 16;
        int row  = row0 + (lane >> 2);
        int slot = lane & 3;
        int srcslot = slot ^ ((row >> 1) & 3);
        const short* src = g + (size_t)row * stride + srcslot * 8;
        __builtin_amdgcn_global_load_lds(
            (const __attribute__((address_space(1))) unsigned int*)src,
            (__attribute__((address_space(3))) unsigned int*)(lds + row0 * 32),
            16, 0, 0);
    }
}

__device__ __forceinline__ void stage128w8(const short* __restrict__ g, int stride,
                                           short* lds, int wid, int lane)
{
    int row0 = wid * 16;
    int row  = row0 + (lane >> 2);
    int slot = lane & 3;
    int srcslot = slot ^ ((row >> 1) & 3);
    const short* src = g + (size_t)row * stride + srcslot * 8;
    __builtin_amdgcn_global_load_lds(
        (const __attribute__((address_space(1))) unsigned int*)src,
        (__attribute__((address_space(3))) unsigned int*)(lds + row0 * 32),
        16, 0, 0);
}

__device__ __forceinline__ f16x8 fragSw(const short* lds, int r, int slot)
{
    return *(const f16x8*)&lds[r * 32 + ((slot ^ ((r >> 1) & 3)) << 3)];
}

// ---------------------------------------------------------------------------
// Kernel 0: fused {transpose x -> xTh fp16} + {W fp32 -> fp16}.
// ---------------------------------------------------------------------------
__global__ __launch_bounds__(256) void transpose_prep(
    const float* __restrict__ x, short* __restrict__ xTh,
    const float* __restrict__ Wq, const float* __restrict__ Wk,
    const float* __restrict__ Wv, short* __restrict__ Wh)
{
    const int id = blockIdx.x;
    const int tid = threadIdx.x;
    __shared__ float tile[64 * 69];

    if (id < 2048) {
        const int b = id & 7;
        const int r = id >> 3;
        const int t0 = (r & 31) * 64, c0 = (r >> 5) * 64;
        const float* xb = x + (size_t)b * Cc * Tt;
        #pragma unroll
        for (int p = 0; p < 4; ++p) {
            int idx = tid + p * 256;
            int cr = idx >> 4, ch = idx & 15;
            float4 v = *(const float4*)&xb[(size_t)(c0 + cr) * Tt + t0 + ch * 4];
            tile[cr * 69 + ch * 4 + 0] = v.x;
            tile[cr * 69 + ch * 4 + 1] = v.y;
            tile[cr * 69 + ch * 4 + 2] = v.z;
            tile[cr * 69 + ch * 4 + 3] = v.w;
        }
        __syncthreads();
        #pragma unroll
        for (int p = 0; p < 4; ++p) {
            int idx = tid + p * 256;
            int t = idx >> 4, cg = idx & 15;
            us4 h;
            h.x = f2h(tile[(cg * 4 + 0) * 69 + t]);
            h.y = f2h(tile[(cg * 4 + 1) * 69 + t]);
            h.z = f2h(tile[(cg * 4 + 2) * 69 + t]);
            h.w = f2h(tile[(cg * 4 + 3) * 69 + t]);
            size_t o = (size_t)b * Tt * Cc + (size_t)(t0 + t) * Cc + c0 + cg * 4;
            *(us4*)&xTh[o] = h;
        }
    } else {
        int i = ((id - 2048) * 256 + tid) * 8;
        int which = i >> 18;
        int rem = i & ((1 << 18) - 1);
        const float* src = which == 0 ? Wq : (which == 1 ? Wk : Wv);
        float4 a = *(const float4*)&src[rem];
        float4 c = *(const float4*)&src[rem + 4];
        us8 h;
        h[0] = f2h(a.x); h[1] = f2h(a.y); h[2] = f2h(a.z); h[3] = f2h(a.w);
        h[4] = f2h(c.x); h[5] = f2h(c.y); h[6] = f2h(c.z); h[7] = f2h(c.w);
        *(us8*)&Wh[i] = h;
    }
}

// ---------------------------------------------------------------------------
// Kernel 1: Q/K projection, 256x128 tile, 512 threads (8 waves), fp16 MFMA,
// 2-phase double-buffered K-loop. b = id&7 (XCD).
// ---------------------------------------------------------------------------
__global__ __launch_bounds__(512) void qk_mfma(
    const short* __restrict__ xTh, const short* __restrict__ Wh_g,
    const float* __restrict__ bq, const float* __restrict__ bk,
    unsigned short* __restrict__ Qh, unsigned short* __restrict__ Kh)
{
    const int id = blockIdx.x;
    const int b = id & 7;
    const int rem = id >> 3;           // 0..63
    const int which = rem >> 5;        // 0..1
    const int r2 = rem & 31;
    const int tb0 = (r2 & 7) * 256;
    const int kb0 = (r2 >> 3) * 128;
    const int tid = threadIdx.x, lane = tid & 63, wid = tid >> 6;
    const int wr = (wid >> 1) * 64, wc = (wid & 1) * 64;

    __shared__ __align__(16) short sbuf[24576];   // 48 KB
    short* As0 = sbuf;            // 256x32
    short* As1 = sbuf + 8192;
    short* Bs0 = sbuf + 16384;    // 128x32
    short* Bs1 = sbuf + 20480;

    const short* Wp = Wh_g + (size_t)which * Kk * Cc;
    const short* Ag = xTh + (size_t)b * Tt * Cc + (size_t)tb0 * Cc;
    const short* Bg = Wp + (size_t)kb0 * Cc;

    f32x4 acc[4][4];
    #pragma unroll
    for (int i = 0; i < 4; ++i)
        #pragma unroll
        for (int j = 0; j < 4; ++j) acc[i][j] = (f32x4){0.f, 0.f, 0.f, 0.f};

    stage256(Ag, Cc, As0, wid, lane);
    stage128w8(Bg, Cc, Bs0, wid, lane);
    __syncthreads();

    int cur = 0;
    for (int step = 0; step < Cc / 32; ++step) {
        short* Ac = cur ? As1 : As0;
        short* Bc = cur ? Bs1 : Bs0;
        if (step + 1 < Cc / 32) {
            int c0 = (step + 1) * 32;
            stage256(Ag + c0, Cc, cur ? As0 : As1, wid, lane);
            stage128w8(Bg + c0, Cc, cur ? Bs0 : Bs1, wid, lane);
        }
        const int fr = lane & 15, slot = lane >> 4;
        f16x8 a4[4], b4[4];
        #pragma unroll
        for (int i = 0; i < 4; ++i) {
            a4[i] = fragSw(Ac, wr + i * 16 + fr, slot);
            b4[i] = fragSw(Bc, wc + i * 16 + fr, slot);
        }
        #pragma unroll
        for (int i = 0; i < 4; ++i)
            #pragma unroll
            for (int j = 0; j < 4; ++j)
                acc[i][j] = MFMA16F(a4[i], b4[j], acc[i][j]);
        __syncthreads();
        cur ^= 1;
    }

    const float* bg = (which == 0) ? bq : bk;
    unsigned short* Oh = ((which == 0) ? Qh : Kh) + (size_t)b * Tt * Kk;
    const int g = lane >> 4;
    #pragma unroll
    for (int j = 0; j < 4; ++j) {
        int k = kb0 + wc + j * 16 + (lane & 15);
        float bias = bg[k];
        #pragma unroll
        for (int i = 0; i < 4; ++i)
            #pragma unroll
            for (int r = 0; r < 4; ++r) {
                int t = tb0 + wr + i * 16 + g * 4 + r;
                Oh[(size_t)t * Kk + k] = f2h(acc[i][j][r] + bias);
            }
    }
}

// ---------------------------------------------------------------------------
// Kernel 2: heterogeneous 512-thread grid.
// ids [0,576):   scores tiles 256x128 -> e fp16 + column partial sums.
// ids [576,832): V projection 256x128 -> Vt.
// ids [832,960): zerofill of fully-masked w chunks [b][q0..q0+64)[1024..2048)
//                — only chunks NOT overlapping the xTh/Wh scratch at the
//                start of the w region: b>=2, or b==1 && q0>=192. The rest
//                stay with norm_pv's zero path. Overlaps scores' MFMA phase
//                (store-BW is idle there), removing ~28 MB from norm_pv.
// ---------------------------------------------------------------------------
__global__ __launch_bounds__(512) void scores_vproj(
    const unsigned short* __restrict__ Qh, const unsigned short* __restrict__ Kh,
    const short* __restrict__ xTh, const short* __restrict__ Wh_g,
    const float* __restrict__ bv,
    unsigned short* __restrict__ e, float* __restrict__ psum,
    short* __restrict__ Vt, float* __restrict__ S)
{
    const int id = blockIdx.x;
    const int tid = threadIdx.x, lane = tid & 63, wid = tid >> 6;
    const int wr = (wid >> 1) * 64, wc = (wid & 1) * 64;

    __shared__ __align__(16) short sbuf[24576];   // 48 KB pool
    short* As0 = sbuf;            // 256x32
    short* As1 = sbuf + 8192;
    short* Bs0 = sbuf + 16384;    // 128x32
    short* Bs1 = sbuf + 20480;

    if (id < 576) {
        // ----- scores role -----
        const int b = id & 7;
        const int rem = id >> 3;           // 0..71 -> (qb, ti), ti <= 2qb+1
        int qb = (int)((sqrtf(4.f * rem + 1.f) - 1.f) * 0.5f);
        while ((qb + 1) * (qb + 2) <= rem) ++qb;
        while (qb * (qb + 1) > rem) --qb;
        const int ti = rem - qb * (qb + 1);
        const int q0 = qb * 256, t0 = ti * 128;
        const bool mm = (ti >= 2 * qb);    // tile may touch the mask

        const short* Qg = (const short*)Qh + (size_t)b * Tt * Kk + (size_t)q0 * Kk;
        const short* Kg = (const short*)Kh + (size_t)b * Tt * Kk + (size_t)t0 * Kk;

        f32x4 acc[4][4];
        #pragma unroll
        for (int i = 0; i < 4; ++i)
            #pragma unroll
            for (int j = 0; j < 4; ++j) acc[i][j] = (f32x4){0.f, 0.f, 0.f, 0.f};

        stage256(Qg, Kk, As0, wid, lane);
        stage128w8(Kg, Kk, Bs0, wid, lane);
        __syncthreads();

        int cur = 0;
        for (int step = 0; step < Kk / 32; ++step) {
            short* Qc = cur ? As1 : As0;
            short* Kc = cur ? Bs1 : Bs0;
            if (step + 1 < Kk / 32) {
                int k0 = (step + 1) * 32;
                stage256(Qg + k0, Kk, cur ? As0 : As1, wid, lane);
                stage128w8(Kg + k0, Kk, cur ? Bs0 : Bs1, wid, lane);
            }
            const int fr = lane & 15, slot = lane >> 4;
            f16x8 qf[4], kf[4];
            #pragma unroll
            for (int i = 0; i < 4; ++i) {
                qf[i] = fragSw(Qc, wr + i * 16 + fr, slot);
                kf[i] = fragSw(Kc, wc + i * 16 + fr, slot);
            }
            #pragma unroll
            for (int i = 0; i < 4; ++i)
                #pragma unroll
                for (int j = 0; j < 4; ++j)
                    acc[i][j] = MFMA16F(qf[i], kf[j], acc[i][j]);
            __syncthreads();
            cur ^= 1;
        }

        unsigned short* eb = e + (size_t)b * Tt * Tt;
        const int fcol = lane & 15, g = lane >> 4;

        // pass 1: psum for all waves; waves wid<4 (rows 0-127) deposit e
        // into the LDS tile [128][136].
        float psumv[4];
        #pragma unroll
        for (int j = 0; j < 4; ++j) {
            int tl = wc + j * 16 + fcol;
            int t = t0 + tl;
            float su = 0.f;
            #pragma unroll
            for (int i = 0; i < 4; ++i)
                #pragma unroll
                for (int r = 0; r < 4; ++r) {
                    int ql = wr + i * 16 + g * 4 + r;
                    int q = q0 + ql;
                    float sv = acc[i][j][r] * SCALE;
                    float ev = __expf(fminf(sv, 11.0f));
                    bool live = (!mm || q >= t);
                    if (live) su += ev;
                    if (wid < 4) sbuf[ql * 136 + tl] = live ? (short)f2h(ev) : (short)0;
                }
            su += __shfl_xor(su, 16, 64);
            su += __shfl_xor(su, 32, 64);
            psumv[j] = su;
        }
        if (lane < 16) {
            const int chunk = qb * 4 + (wid >> 1);
            #pragma unroll
            for (int j = 0; j < 4; ++j) {
                int t = t0 + wc + j * 16 + lane;
                psum[((size_t)b * 32 + chunk) * Tt + t] = psumv[j];
            }
        }
        __syncthreads();

        // store rows 0..127 (coalesced us8 rows)
        #pragma unroll
        for (int c = 0; c < 4; ++c) {
            int chunk = tid + 512 * c;          // 0..2047
            int ql = chunk >> 4, toct = chunk & 15;
            us8 v = *(const us8*)&sbuf[ql * 136 + toct * 8];
            *(us8*)&eb[(size_t)(q0 + ql) * Tt + t0 + toct * 8] = v;
        }
        __syncthreads();

        // pass 2: waves wid>=4 deposit rows 128-255 (shifted by -128)
        if (wid >= 4) {
            #pragma unroll
            for (int j = 0; j < 4; ++j) {
                int tl = wc + j * 16 + fcol;
                int t = t0 + tl;
                #pragma unroll
                for (int i = 0; i < 4; ++i)
                    #pragma unroll
                    for (int r = 0; r < 4; ++r) {
                        int ql = wr + i * 16 + g * 4 + r;
                        int q = q0 + ql;
                        float sv = acc[i][j][r] * SCALE;
                        float ev = __expf(fminf(sv, 11.0f));
                        bool live = (!mm || q >= t);
                        sbuf[(ql - 128) * 136 + tl] = live ? (short)f2h(ev) : (short)0;
                    }
            }
        }
        __syncthreads();

        // store rows 128..255
        #pragma unroll
        for (int c = 0; c < 4; ++c) {
            int chunk = tid + 512 * c;
            int ql = chunk >> 4, toct = chunk & 15;
            us8 v = *(const us8*)&sbuf[ql * 136 + toct * 8];
            *(us8*)&eb[(size_t)(q0 + 128 + ql) * Tt + t0 + toct * 8] = v;
        }
    } else if (id < 832) {
        // ----- V projection role: 256 v-rows x 128 t-cols -----
        const int id2 = id - 576;
        const int b = id2 & 7;
        const int r2 = id2 >> 3;           // 0..31
        const int tb0 = (r2 & 15) * 128;
        const int kb0 = (r2 >> 4) * 256;

        const short* Wp = Wh_g + (size_t)2 * Kk * Cc;
        const short* Ag = Wp + (size_t)kb0 * Cc;
        const short* Bg = xTh + (size_t)b * Tt * Cc + (size_t)tb0 * Cc;

        f32x4 acc[4][4];
        #pragma unroll
        for (int i = 0; i < 4; ++i)
            #pragma unroll
            for (int j = 0; j < 4; ++j) acc[i][j] = (f32x4){0.f, 0.f, 0.f, 0.f};

        stage256(Ag, Cc, As0, wid, lane);
        stage128w8(Bg, Cc, Bs0, wid, lane);
        __syncthreads();

        int cur = 0;
        for (int step = 0; step < Cc / 32; ++step) {
            short* Ac = cur ? As1 : As0;
            short* Bc = cur ? Bs1 : Bs0;
            if (step + 1 < Cc / 32) {
                int c0 = (step + 1) * 32;
                stage256(Ag + c0, Cc, cur ? As0 : As1, wid, lane);
                stage128w8(Bg + c0, Cc, cur ? Bs0 : Bs1, wid, lane);
            }
            const int fr = lane & 15, slot = lane >> 4;
            f16x8 a4[4], b4[4];
            #pragma unroll
            for (int i = 0; i < 4; ++i) {
                a4[i] = fragSw(Ac, wr + i * 16 + fr, slot);
                b4[i] = fragSw(Bc, wc + i * 16 + fr, slot);
            }
            #pragma unroll
            for (int i = 0; i < 4; ++i)
                #pragma unroll
                for (int j = 0; j < 4; ++j)
                    acc[i][j] = MFMA16F(a4[i], b4[j], acc[i][j]);
            __syncthreads();
            cur ^= 1;
        }

        short* Vb = Vt + (size_t)b * Kk * Tt;
        const int g = lane >> 4;
        #pragma unroll
        for (int i = 0; i < 4; ++i)
            #pragma unroll
            for (int r = 0; r < 4; ++r) {
                int vv = kb0 + wr + i * 16 + g * 4 + r;
                float bias = bv[vv];
                #pragma unroll
                for (int j = 0; j < 4; ++j) {
                    int t = tb0 + wc + j * 16 + (lane & 15);
                    Vb[(size_t)vv * Tt + t] = (short)f2h(acc[i][j][r] + bias);
                }
            }
    } else {
        // ----- zerofill role: fully-masked w chunks outside the scratch -----
        const int id2 = id - 832;          // 0..127
        const int b = id2 & 7;
        const int qc = id2 >> 3;           // 0..15 -> q0 = qc*64 (all <= 960)
        const int q0 = qc * 64;
        if (!(b >= 2 || (b == 1 && q0 >= 192))) return;  // overlaps scratch
        float* Sb = S + (size_t)b * Tt * Tt;
        f32x4 z = (f32x4){0.f, 0.f, 0.f, 0.f};
        // chunk: rows q0..q0+63, cols 1024..2047 (64 x 1024 floats)
        #pragma unroll 4
        for (int it = 0; it < 32; ++it) {
            int idx = it * 512 + tid;      // 0..16383
            int row = idx >> 8;            // /256 float4-groups per row
            int c4  = (idx & 255) * 4;
            __builtin_nontemporal_store(z,
                (f32x4*)&Sb[(size_t)(q0 + row) * Tt + 1024 + c4]);
        }
    }
}

// ---------------------------------------------------------------------------
// Kernel 3: fused {combine psum -> inv} + {V *= inv[t]}.
// ---------------------------------------------------------------------------
__global__ __launch_bounds__(256) void inv_vscale(
    const float* __restrict__ psum, float* __restrict__ mi,
    unsigned short* __restrict__ Vt)
{
    const int id = blockIdx.x;
    const int b  = id & 7;
    const int tc = (id >> 3) & 7;
    const int vq = id >> 6;
    const int tid = threadIdx.x;
    const int t = tc * 256 + tid;

    __shared__ float invs[256];
    float s = 0.f;
    for (int c = (t >> 6); c < 32; ++c)
        s += psum[((size_t)b * 32 + c) * Tt + t];
    float inv = 1.0f / s;
    invs[tid] = inv;
    if (vq == 0) mi[b * Tt + t] = inv;
    __syncthreads();

    const int toff = (tid & 63) * 4;
    const float i0 = invs[toff], i1 = invs[toff + 1];
    const float i2 = invs[toff + 2], i3 = invs[toff + 3];
    unsigned short* Vb = (unsigned short*)Vt + (size_t)b * Kk * Tt + tc * 256;
    #pragma unroll 4
    for (int it = 0; it < 32; ++it) {
        int row = vq * 128 + (tid >> 6) + it * 4;
        unsigned short* p = Vb + (size_t)row * Tt + toff;
        us4 v = *(us4*)p;
        v.x = f2h(h2f(v.x) * i0);
        v.y = f2h(h2f(v.y) * i1);
        v.z = f2h(h2f(v.z) * i2);
        v.w = f2h(h2f(v.w) * i3);
        *(us4*)p = v;
    }
}

// ---------------------------------------------------------------------------
// Kernel 4: fused heterogeneous grid.
// ids [0,512):  pv role (heavy-first qi order); ids [512,1024): norm role.
// Fully-masked chunks pre-zeroed by scores_vproj early-return here.
// w/out0 stores are non-temporal (never re-read) to keep L2 for e/V.
// ---------------------------------------------------------------------------
__global__ __launch_bounds__(256) void norm_pv(
    const short* __restrict__ Vt, const unsigned short* __restrict__ e,
    const float* __restrict__ mi, float* __restrict__ S,
    float* __restrict__ out0)
{
    const int id = blockIdx.x;
    const int tid = threadIdx.x;

    __shared__ __align__(16) short Vs[2][128 * 32];
    __shared__ __align__(16) short Ws[2][128 * 32];

    if (id < 512) {
        // ----- pv role -----
        const int b = id & 7;
        const int rem = id >> 3;           // 0..63
        const int vt = rem & 3, qi = 15 - (rem >> 2);   // heavy first
        const int qb0 = qi * 128, vb0 = vt * 128;
        const int lane = tid & 63, wid = tid >> 6;
        const int wr = (wid >> 1) * 64, wc = (wid & 1) * 64;

        const short* Vg = Vt + (size_t)b * Kk * Tt + (size_t)vb0 * Tt;
        const short* Wg = (const short*)e + ((size_t)b * Tt + qb0) * Tt;

        f32x4 acc[4][4];
        #pragma unroll
        for (int i = 0; i < 4; ++i)
            #pragma unroll
            for (int j = 0; j < 4; ++j) acc[i][j] = (f32x4){0.f, 0.f, 0.f, 0.f};

        const int nsteps = (qb0 + 128) / 32;
        stageP(Vg, Tt, Vs[0], wid, lane);
        stageP(Wg, Tt, Ws[0], wid, lane);
        __syncthreads();

        int cur = 0;
        for (int s = 0; s < nsteps; ++s) {
            if (s + 1 < nsteps) {
                int t0 = (s + 1) * 32;
                stageP(Vg + t0, Tt, Vs[cur ^ 1], wid, lane);
                stageP(Wg + t0, Tt, Ws[cur ^ 1], wid, lane);
            }
            const int fr = lane & 15, slot = lane >> 4;
            f16x8 av[4], bw[4];
            #pragma unroll
            for (int i = 0; i < 4; ++i) {
                av[i] = fragSw(Vs[cur], wr + i * 16 + fr, slot);
                bw[i] = fragSw(Ws[cur], wc + i * 16 + fr, slot);
            }
            #pragma unroll
            for (int i = 0; i < 4; ++i)
                #pragma unroll
                for (int j = 0; j < 4; ++j)
                    acc[i][j] = MFMA16F(av[i], bw[j], acc[i][j]);
            __syncthreads();
            cur ^= 1;
        }

        float* ob = out0 + (size_t)b * Kk * Tt;
        #pragma unroll
        for (int i = 0; i < 4; ++i)
            #pragma unroll
            for (int j = 0; j < 4; ++j)
                #pragma unroll
                for (int r = 0; r < 4; ++r) {
                    int vv = vb0 + wr + i * 16 + (lane >> 4) * 4 + r;
                    int q  = qb0 + wc + j * 16 + (lane & 15);
                    __builtin_nontemporal_store(acc[i][j][r],
                                                &ob[(size_t)vv * Tt + q]);
                }
    } else {
        // ----- norm role -----
        const int id2 = id - 512;
        const int b = id2 & 7;
        const int rem = id2 >> 3;          // 0..63
        const int tb = rem & 1;            // 1024-col t half
        const int qc = rem >> 1;           // 0..31, 64-row q chunk
        const int t0blk = tb * 1024;
        const int t = t0blk + tid * 4;
        const int q0 = qc * 64;
        float* Sb = S + (size_t)b * Tt * Tt;

        if (q0 + 64 <= t0blk) {            // fully masked
            if (b >= 2 || (b == 1 && q0 >= 192)) return;  // pre-zeroed
            f32x4 z = (f32x4){0.f, 0.f, 0.f, 0.f};
            for (int q = q0; q < q0 + 64; ++q)
                __builtin_nontemporal_store(z, (f32x4*)&Sb[(size_t)q * Tt + t]);
        } else {
            float4 inv = *(const float4*)&mi[b * Tt + t];
            const unsigned short* eb = e + (size_t)b * Tt * Tt;
            for (int q = q0; q < q0 + 64; ++q) {
                f32x4 o = (f32x4){0.f, 0.f, 0.f, 0.f};
                if (q >= t + 3) {          // all 4 live
                    us4 ev = *(const us4*)&eb[(size_t)q * Tt + t];
                    o[0] = h2f(ev.x) * inv.x; o[1] = h2f(ev.y) * inv.y;
                    o[2] = h2f(ev.z) * inv.z; o[3] = h2f(ev.w) * inv.w;
                } else if (q >= t) {       // partial
                    us4 ev = *(const us4*)&eb[(size_t)q * Tt + t];
                    o[0] = h2f(ev.x) * inv.x;
                    if (q >= t + 1) o[1] = h2f(ev.y) * inv.y;
                    if (q >= t + 2) o[2] = h2f(ev.z) * inv.z;
                }
                __builtin_nontemporal_store(o, (f32x4*)&Sb[(size_t)q * Tt + t]);
            }
        }
    }
}

// ---------------------------------------------------------------------------
extern "C" void kernel_launch(void* const* d_in, const int* in_sizes, int n_in,
                              void* d_out, int out_size, void* d_ws, size_t ws_size,
                              hipStream_t stream)
{
    const float* x  = (const float*)d_in[0];
    const float* Wq = (const float*)d_in[1];
    const float* bq = (const float*)d_in[2];
    const float* Wk = (const float*)d_in[3];
    const float* bk = (const float*)d_in[4];
    const float* Wv = (const float*)d_in[5];
    const float* bv = (const float*)d_in[6];

    float* out0 = (float*)d_out;                        // [B][V][T]
    float* w    = out0 + (size_t)Bsz * Kk * Tt;         // [B][T][T]

    // Scratch living at the START of the w output region (first ~4.59M
    // floats: b=0's w + b=1 rows <192); dead before any w writes to that
    // span (norm_pv's non-pre-zeroed chunks + live region).
    short* xTh  = (short*)w;                            // [B][T][C] fp16
    short* Wh_g = xTh + (size_t)Bsz * Tt * Cc;          // [3][K][C] fp16

    const size_t N = (size_t)Bsz * Tt * Kk;
    unsigned short* Qh = (unsigned short*)d_ws;         // [B][T][K] fp16
    unsigned short* Kh = Qh + N;
    short* Vt = (short*)(Kh + N);                       // [B][V][T] fp16
    float* psum = (float*)(Vt + N);                     // [B][32][T]
    float* mi   = psum + (size_t)Bsz * 32 * Tt;         // [B][T]
    unsigned short* e = (unsigned short*)(mi + (size_t)Bsz * Tt); // [B][T][T] fp16

    transpose_prep<<<dim3(2048 + 384), dim3(256), 0, stream>>>(
        x, xTh, Wq, Wk, Wv, Wh_g);
    qk_mfma<<<dim3(512), dim3(512), 0, stream>>>(
        xTh, Wh_g, bq, bk, Qh, Kh);
    scores_vproj<<<dim3(576 + 256 + 128), dim3(512), 0, stream>>>(
        Qh, Kh, xTh, Wh_g, bv, e, psum, Vt, w);
    inv_vscale<<<dim3(256), dim3(256), 0, stream>>>(psum, mi, (unsigned short*)Vt);
    norm_pv<<<dim3(1024), dim3(256), 0, stream>>>(Vt, e, mi, w, out0);
}